// Round 2
// baseline (874.740 us; speedup 1.0000x reference)
//
#include <hip/hip_runtime.h>
#include <math.h>

typedef __attribute__((ext_vector_type(8))) short short8;
typedef __attribute__((ext_vector_type(4))) float f32x4;
typedef __attribute__((ext_vector_type(4))) unsigned short us4;
typedef __attribute__((ext_vector_type(4))) float fl4;

#define B_ 2
#define S_ 2048
#define H_ 16
#define D_ 128
#define HID 2048

__device__ __forceinline__ unsigned short f2bf(float f){
  unsigned u = __builtin_bit_cast(unsigned, f);
  u += 0x7fffu + ((u >> 16) & 1u);
  return (unsigned short)(u >> 16);
}
__device__ __forceinline__ float bf2f(unsigned short u){
  unsigned x = ((unsigned)u) << 16;
  return __builtin_bit_cast(float, x);
}

// async global -> LDS, 16 bytes per lane (dest must be linear: base + lane*16)
__device__ __forceinline__ void g2lds16(const unsigned short* g, unsigned short* l){
  __builtin_amdgcn_global_load_lds(
      (const __attribute__((address_space(1))) unsigned int*)g,
      (__attribute__((address_space(3))) unsigned int*)l, 16, 0, 0);
}

// ---------- f32 -> bf16 convert (4 elems/thread) ----------
__global__ void cvt_k(const float* __restrict__ src, unsigned short* __restrict__ dst){
  int i = (blockIdx.x * 256 + threadIdx.x) * 4;
  fl4 v = *(const fl4*)(src + i);
  us4 o;
  #pragma unroll
  for (int t = 0; t < 4; t++) o[t] = f2bf(v[t]);
  *(us4*)(dst + i) = o;
}

// ---------- cos/sin tables from freqs ----------
__global__ void tab_k(const float* __restrict__ freqs, float* __restrict__ ctab,
                      float* __restrict__ stab){
  int i = blockIdx.x * 256 + threadIdx.x;
  float f = freqs[i];
  ctab[i] = cosf(f);
  stab[i] = sinf(f);
}

// ---------- GEMM: C[i][j] = sum_k A[i][k] * B[j][k]  (bf16 row-major, both K-major) ----------
// EPI==1: z in {0,1} picks (B0,O0)/(B1,O1); writes bf16 scattered to [B,H,S,D] (Q,K)
// EPI==2: A=Wv (rows=features), B=x (rows=tokens); writes bf16 V^T to [B,H,D,S]
// EPI==0: writes f32 to Of[i*HID + j]
template<int EPI>
__global__ __launch_bounds__(256) void gemm_k(
    const unsigned short* __restrict__ A,
    const unsigned short* __restrict__ B0,
    const unsigned short* __restrict__ B1,
    unsigned short* __restrict__ O0,
    unsigned short* __restrict__ O1,
    float* __restrict__ Of)
{
  __shared__ __align__(16) unsigned short As[128 * 32];
  __shared__ __align__(16) unsigned short Bs[128 * 32];
  const int tid = threadIdx.x;
  const int l = tid & 63, lg = l >> 4, lr = l & 15;
  const int w = tid >> 6, wm = w & 1, wn = w >> 1;
  const int m0 = blockIdx.x * 128, n0 = blockIdx.y * 128;
  const unsigned short* Bm = (EPI == 1 && blockIdx.z == 1) ? B1 : B0;

  f32x4 acc[4][4];
  #pragma unroll
  for (int i = 0; i < 4; i++)
    #pragma unroll
    for (int j = 0; j < 4; j++)
      acc[i][j] = f32x4{0.f, 0.f, 0.f, 0.f};

  // staging map: lane writes 16B at As + tid*16B -> row = tid>>2, col8 = tid&3
  const unsigned short* gA = A  + (size_t)(m0 + (tid >> 2)) * HID + (tid & 3) * 8;
  const unsigned short* gB = Bm + (size_t)(n0 + (tid >> 2)) * HID + (tid & 3) * 8;
  unsigned short* lA = As + tid * 8;
  unsigned short* lB = Bs + tid * 8;

  for (int kt = 0; kt < HID; kt += 32){
    __syncthreads();                       // prev iter's LDS reads done
    g2lds16(gA + kt,            lA);
    g2lds16(gA + 64 * HID + kt, lA + 2048);
    g2lds16(gB + kt,            lB);
    g2lds16(gB + 64 * HID + kt, lB + 2048);
    __syncthreads();                       // barrier drains vmcnt -> tiles ready

    short8 aF[4], bF[4];
    #pragma unroll
    for (int mi = 0; mi < 4; mi++)
      aF[mi] = *(const short8*)(As + (wm * 64 + mi * 16 + lr) * 32 + lg * 8);
    #pragma unroll
    for (int ni = 0; ni < 4; ni++)
      bF[ni] = *(const short8*)(Bs + (wn * 64 + ni * 16 + lr) * 32 + lg * 8);
    #pragma unroll
    for (int mi = 0; mi < 4; mi++)
      #pragma unroll
      for (int ni = 0; ni < 4; ni++)
        acc[mi][ni] = __builtin_amdgcn_mfma_f32_16x16x32_bf16(aF[mi], bF[ni], acc[mi][ni], 0, 0, 0);
  }

  if (EPI == 1){
    unsigned short* O = blockIdx.z ? O1 : O0;
    #pragma unroll
    for (int mi = 0; mi < 4; mi++)
      #pragma unroll
      for (int r = 0; r < 4; r++){
        int i = m0 + wm * 64 + mi * 16 + lg * 4 + r;
        int b = i >> 11, s = i & 2047;
        #pragma unroll
        for (int ni = 0; ni < 4; ni++){
          int j = n0 + wn * 64 + ni * 16 + lr;
          int h = j >> 7, d = j & 127;
          O[((size_t)(b * H_ + h) * S_ + s) * D_ + d] = f2bf(acc[mi][ni][r]);
        }
      }
  } else if (EPI == 2){
    #pragma unroll
    for (int mi = 0; mi < 4; mi++)
      #pragma unroll
      for (int r = 0; r < 4; r++){
        int gi = m0 + wm * 64 + mi * 16 + lg * 4 + r;   // feature j
        int h = gi >> 7, d = gi & 127;
        #pragma unroll
        for (int ni = 0; ni < 4; ni++){
          int gj = n0 + wn * 64 + ni * 16 + lr;         // token i
          int b = gj >> 11, s = gj & 2047;
          O0[((size_t)(b * H_ + h) * D_ + d) * S_ + s] = f2bf(acc[mi][ni][r]);
        }
      }
  } else {
    #pragma unroll
    for (int mi = 0; mi < 4; mi++)
      #pragma unroll
      for (int r = 0; r < 4; r++){
        int i = m0 + wm * 64 + mi * 16 + lg * 4 + r;
        #pragma unroll
        for (int ni = 0; ni < 4; ni++){
          int j = n0 + wn * 64 + ni * 16 + lr;
          Of[(size_t)i * HID + j] = acc[mi][ni][r];
        }
      }
  }
}

// ---------- in-place RoPE on Q and K ([B,H,S,D] bf16) ----------
__global__ void rope_k(unsigned short* __restrict__ Q, unsigned short* __restrict__ K,
                       const float* __restrict__ ctab, const float* __restrict__ stab){
  int idx = blockIdx.x * 256 + threadIdx.x;
  unsigned short* P = (idx >= (1 << 20)) ? K : Q;
  int e  = idx & ((1 << 20) - 1);
  int g  = e & 15;
  int s  = (e >> 4) & 2047;
  int bh = e >> 15;
  int d0 = g * 4;
  size_t base = ((size_t)bh * S_ + s) * D_;
  us4 qa = *(us4*)(P + base + d0);
  us4 qb = *(us4*)(P + base + d0 + 64);
  fl4 ca = *(const fl4*)(ctab + s * D_ + d0);
  fl4 sa = *(const fl4*)(stab + s * D_ + d0);
  fl4 cb = *(const fl4*)(ctab + s * D_ + d0 + 64);
  fl4 sb = *(const fl4*)(stab + s * D_ + d0 + 64);
  us4 oa, ob;
  #pragma unroll
  for (int t = 0; t < 4; t++){
    float xa = bf2f(qa[t]), xb = bf2f(qb[t]);
    oa[t] = f2bf(xa * ca[t] - xb * sa[t]);
    ob[t] = f2bf(xb * cb[t] + xa * sb[t]);
  }
  *(us4*)(P + base + d0)      = oa;
  *(us4*)(P + base + d0 + 64) = ob;
}

// ---------- flash attention: swapped QK^T, zero LDS, zero barriers ----------
// Per wave: 16 q-rows. Lane l: softmax column q = q0 + (l&15); S^T fragment rows k.
__global__ __launch_bounds__(256) void attn_k(
    const unsigned short* __restrict__ Q,     // [B,H,S,D] (rope'd)
    const unsigned short* __restrict__ Kg,    // [B,H,S,D] (rope'd)
    const unsigned short* __restrict__ Vt,    // [B,H,D,S]
    const float* __restrict__ mask,           // [S,S]
    const float* __restrict__ alibi,          // [H,S]
    unsigned short* __restrict__ Ctx)         // [B,S,H,D]
{
  const int tid = threadIdx.x;
  const int l = tid & 63, lg = l >> 4, lr = l & 15;
  const int w = tid >> 6;
  const int bh = blockIdx.y, b = bh >> 4, h = bh & 15;
  const int q0 = blockIdx.x * 64 + w * 16;
  const size_t hb = (size_t)bh * S_ * D_;
  const float* mrow = mask + (size_t)(q0 + lr) * S_;   // this lane's q-column row
  const float* al = alibi + h * S_;
  const int sidx = (l & 48) + ((l & 48) >> 2);         // lane holding stats for q'=4*lg+r
  const float SCL2E = 0.08838834764831845f * 1.4426950408889634f;
  const float L2E = 1.4426950408889634f;

  short8 qf[4];
  #pragma unroll
  for (int c = 0; c < 4; c++)
    qf[c] = *(const short8*)(Q + hb + (size_t)(q0 + lr) * D_ + c * 32 + lg * 8);

  f32x4 acc[8];
  #pragma unroll
  for (int c = 0; c < 8; c++) acc[c] = f32x4{0.f, 0.f, 0.f, 0.f};
  float mr = -1e30f, lsum = 0.f;

  for (int t = 0; t < 64; t++){
    const int kv0 = t * 32;
    // S^T[k][q] = K · Q^T : A-frag = K rows, B-frag = Q rows
    f32x4 s0 = f32x4{0.f, 0.f, 0.f, 0.f}, s1 = s0;
    #pragma unroll
    for (int c = 0; c < 4; c++){
      short8 kf = *(const short8*)(Kg + hb + (size_t)(kv0 + lr) * D_ + c * 32 + lg * 8);
      s0 = __builtin_amdgcn_mfma_f32_16x16x32_bf16(kf, qf[c], s0, 0, 0, 0);
    }
    #pragma unroll
    for (int c = 0; c < 4; c++){
      short8 kf = *(const short8*)(Kg + hb + (size_t)(kv0 + 16 + lr) * D_ + c * 32 + lg * 8);
      s1 = __builtin_amdgcn_mfma_f32_16x16x32_bf16(kf, qf[c], s1, 0, 0, 0);
    }

    // lane holds S^T[k = kv0 + 4*lg + r (+16)][q = q0 + lr]
    fl4 mk0 = *(const fl4*)(mrow + kv0 + 4 * lg);
    fl4 mk1 = *(const fl4*)(mrow + kv0 + 16 + 4 * lg);
    fl4 aa0 = *(const fl4*)(al + kv0 + 4 * lg);
    fl4 aa1 = *(const fl4*)(al + kv0 + 16 + 4 * lg);
    float x0[4], x1[4];
    #pragma unroll
    for (int r = 0; r < 4; r++){
      x0[r] = fmaf(s0[r], SCL2E, (mk0[r] + aa0[r]) * L2E);
      x1[r] = fmaf(s1[r], SCL2E, (mk1[r] + aa1[r]) * L2E);
    }
    float mx = fmaxf(fmaxf(fmaxf(x0[0], x0[1]), fmaxf(x0[2], x0[3])),
                     fmaxf(fmaxf(x1[0], x1[1]), fmaxf(x1[2], x1[3])));
    mx = fmaxf(mx, __shfl_xor(mx, 16));
    mx = fmaxf(mx, __shfl_xor(mx, 32));
    float mnew = fmaxf(mr, mx);
    float alpha = exp2f(mr - mnew);
    float p0[4], p1[4], ps = 0.f;
    #pragma unroll
    for (int r = 0; r < 4; r++){
      p0[r] = exp2f(x0[r] - mnew);
      p1[r] = exp2f(x1[r] - mnew);
      ps += p0[r] + p1[r];
    }
    ps += __shfl_xor(ps, 16);
    ps += __shfl_xor(ps, 32);
    lsum = lsum * alpha + ps;
    mr = mnew;

    // pack P(k<16) lo | P(k>=16) hi, per reg r (k = 4*g' + r within half)
    int pk[4];
    #pragma unroll
    for (int r = 0; r < 4; r++)
      pk[r] = ((int)(unsigned)f2bf(p1[r]) << 16) | (int)(unsigned)f2bf(p0[r]);

    // rescale acc rows (row q' = 4*lg + r needs alpha from lane sidx+r)
    float ar[4];
    #pragma unroll
    for (int r = 0; r < 4; r++) ar[r] = __shfl(alpha, sidx + r);
    #pragma unroll
    for (int c = 0; c < 8; c++)
      #pragma unroll
      for (int r = 0; r < 4; r++) acc[c][r] *= ar[r];

    // redistribute: lane needs P[q=lr][k = 8*lg + j] as A-frag
    const int srcb = lr + ((lg & 1) << 5);
    short8 af;
    #pragma unroll
    for (int j = 0; j < 8; j++){
      int wv = __shfl(pk[j & 3], srcb + ((j >> 2) << 4));
      af[j] = (short)((l & 32) ? ((unsigned)wv >> 16) : ((unsigned)wv & 0xffffu));
    }

    // PV: acc[c] += P(16x32) · V(32 x 16-chunk c), V^T rows are k-contiguous
    #pragma unroll
    for (int c = 0; c < 8; c++){
      short8 vf = *(const short8*)(Vt + hb + (size_t)(c * 16 + lr) * S_ + kv0 + lg * 8);
      acc[c] = __builtin_amdgcn_mfma_f32_16x16x32_bf16(af, vf, acc[c], 0, 0, 0);
    }
  }

  float inv = 1.f / lsum;
  float ir[4];
  #pragma unroll
  for (int r = 0; r < 4; r++) ir[r] = __shfl(inv, sidx + r);
  #pragma unroll
  for (int r = 0; r < 4; r++){
    const int qg = q0 + 4 * lg + r;
    const size_t ob = ((size_t)(b * S_ + qg) * H_ + h) * D_;
    #pragma unroll
    for (int c = 0; c < 8; c++)
      Ctx[ob + c * 16 + lr] = f2bf(acc[c][r] * ir[r]);
  }
}

extern "C" void kernel_launch(void* const* d_in, const int* in_sizes, int n_in,
                              void* d_out, int out_size, void* d_ws, size_t ws_size,
                              hipStream_t stream){
  const float* x     = (const float*)d_in[0];
  const float* mask  = (const float*)d_in[1];
  const float* alibi = (const float*)d_in[2];
  const float* freqs = (const float*)d_in[3];
  const float* Wq    = (const float*)d_in[4];
  const float* Wk    = (const float*)d_in[5];
  const float* Wv    = (const float*)d_in[6];
  const float* Wo    = (const float*)d_in[7];
  float* out = (float*)d_out;

  unsigned short* ws  = (unsigned short*)d_ws;
  unsigned short* xb  = ws;                    // 8388608 elems (reused as ctx)
  unsigned short* wqb = ws + 8388608;
  unsigned short* wkb = ws + 12582912;
  unsigned short* wvb = ws + 16777216;
  unsigned short* wob = ws + 20971520;
  unsigned short* Qb  = ws + 25165824;
  unsigned short* Kb  = ws + 33554432;
  unsigned short* Vb  = ws + 41943040;         // holds V^T [B,H,D,S]
  unsigned short* ctx = xb;                    // alias: x consumed after projections
  float* ctab = (float*)(ws + 50331648);
  float* stab = ctab + 262144;

  cvt_k<<<8192, 256, 0, stream>>>(x,  xb);
  cvt_k<<<4096, 256, 0, stream>>>(Wq, wqb);
  cvt_k<<<4096, 256, 0, stream>>>(Wk, wkb);
  cvt_k<<<4096, 256, 0, stream>>>(Wv, wvb);
  cvt_k<<<4096, 256, 0, stream>>>(Wo, wob);
  tab_k<<<1024, 256, 0, stream>>>(freqs, ctab, stab);

  gemm_k<1><<<dim3(32, 16, 2), 256, 0, stream>>>(xb, wqb, wkb, Qb, Kb, nullptr);
  gemm_k<2><<<dim3(16, 32, 1), 256, 0, stream>>>(wvb, xb, nullptr, Vb, nullptr, nullptr);
  rope_k<<<8192, 256, 0, stream>>>(Qb, Kb, ctab, stab);
  attn_k<<<dim3(32, 32), 256, 0, stream>>>(Qb, Kb, Vb, mask, alibi, ctx);
  gemm_k<0><<<dim3(32, 16, 1), 256, 0, stream>>>(ctx, wob, nullptr, nullptr, nullptr, out);
}

// Round 3
// 573.096 us; speedup vs baseline: 1.5263x; 1.5263x over previous
//
#include <hip/hip_runtime.h>
#include <math.h>

typedef __attribute__((ext_vector_type(8))) short short8;
typedef __attribute__((ext_vector_type(4))) float f32x4;
typedef __attribute__((ext_vector_type(4))) unsigned short us4;
typedef __attribute__((ext_vector_type(4))) float fl4;

#define B_ 2
#define S_ 2048
#define H_ 16
#define D_ 128
#define HID 2048

__device__ __forceinline__ unsigned short f2bf(float f){
  unsigned u = __builtin_bit_cast(unsigned, f);
  u += 0x7fffu + ((u >> 16) & 1u);
  return (unsigned short)(u >> 16);
}
__device__ __forceinline__ float bf2f(unsigned short u){
  unsigned x = ((unsigned)u) << 16;
  return __builtin_bit_cast(float, x);
}

// async global -> LDS, 16 bytes per lane (dest must be linear: base + lane*16)
__device__ __forceinline__ void g2lds16(const unsigned short* g, unsigned short* l){
  __builtin_amdgcn_global_load_lds(
      (const __attribute__((address_space(1))) unsigned int*)g,
      (__attribute__((address_space(3))) unsigned int*)l, 16, 0, 0);
}

// ---------- f32 -> bf16 convert (4 elems/thread) ----------
__global__ void cvt_k(const float* __restrict__ src, unsigned short* __restrict__ dst){
  int i = (blockIdx.x * 256 + threadIdx.x) * 4;
  fl4 v = *(const fl4*)(src + i);
  us4 o;
  #pragma unroll
  for (int t = 0; t < 4; t++) o[t] = f2bf(v[t]);
  *(us4*)(dst + i) = o;
}

// ---------- cos/sin tables from freqs ----------
__global__ void tab_k(const float* __restrict__ freqs, float* __restrict__ ctab,
                      float* __restrict__ stab){
  int i = blockIdx.x * 256 + threadIdx.x;
  float f = freqs[i];
  ctab[i] = cosf(f);
  stab[i] = sinf(f);
}

// ---------- GEMM: C[i][j] = sum_k A[i][k] * B[j][k]  (bf16 row-major, both K-major) ----------
template<int EPI>
__global__ __launch_bounds__(256) void gemm_k(
    const unsigned short* __restrict__ A,
    const unsigned short* __restrict__ B0,
    const unsigned short* __restrict__ B1,
    unsigned short* __restrict__ O0,
    unsigned short* __restrict__ O1,
    float* __restrict__ Of)
{
  __shared__ __align__(16) unsigned short As[128 * 32];
  __shared__ __align__(16) unsigned short Bs[128 * 32];
  const int tid = threadIdx.x;
  const int l = tid & 63, lg = l >> 4, lr = l & 15;
  const int w = tid >> 6, wm = w & 1, wn = w >> 1;
  const int m0 = blockIdx.x * 128, n0 = blockIdx.y * 128;
  const unsigned short* Bm = (EPI == 1 && blockIdx.z == 1) ? B1 : B0;

  f32x4 acc[4][4];
  #pragma unroll
  for (int i = 0; i < 4; i++)
    #pragma unroll
    for (int j = 0; j < 4; j++)
      acc[i][j] = f32x4{0.f, 0.f, 0.f, 0.f};

  const unsigned short* gA = A  + (size_t)(m0 + (tid >> 2)) * HID + (tid & 3) * 8;
  const unsigned short* gB = Bm + (size_t)(n0 + (tid >> 2)) * HID + (tid & 3) * 8;
  unsigned short* lA = As + tid * 8;
  unsigned short* lB = Bs + tid * 8;

  for (int kt = 0; kt < HID; kt += 32){
    __syncthreads();
    g2lds16(gA + kt,            lA);
    g2lds16(gA + 64 * HID + kt, lA + 2048);
    g2lds16(gB + kt,            lB);
    g2lds16(gB + 64 * HID + kt, lB + 2048);
    __syncthreads();

    short8 aF[4], bF[4];
    #pragma unroll
    for (int mi = 0; mi < 4; mi++)
      aF[mi] = *(const short8*)(As + (wm * 64 + mi * 16 + lr) * 32 + lg * 8);
    #pragma unroll
    for (int ni = 0; ni < 4; ni++)
      bF[ni] = *(const short8*)(Bs + (wn * 64 + ni * 16 + lr) * 32 + lg * 8);
    #pragma unroll
    for (int mi = 0; mi < 4; mi++)
      #pragma unroll
      for (int ni = 0; ni < 4; ni++)
        acc[mi][ni] = __builtin_amdgcn_mfma_f32_16x16x32_bf16(aF[mi], bF[ni], acc[mi][ni], 0, 0, 0);
  }

  if (EPI == 1){
    unsigned short* O = blockIdx.z ? O1 : O0;
    #pragma unroll
    for (int mi = 0; mi < 4; mi++)
      #pragma unroll
      for (int r = 0; r < 4; r++){
        int i = m0 + wm * 64 + mi * 16 + lg * 4 + r;
        int b = i >> 11, s = i & 2047;
        #pragma unroll
        for (int ni = 0; ni < 4; ni++){
          int j = n0 + wn * 64 + ni * 16 + lr;
          int h = j >> 7, d = j & 127;
          O[((size_t)(b * H_ + h) * S_ + s) * D_ + d] = f2bf(acc[mi][ni][r]);
        }
      }
  } else if (EPI == 2){
    #pragma unroll
    for (int mi = 0; mi < 4; mi++)
      #pragma unroll
      for (int r = 0; r < 4; r++){
        int gi = m0 + wm * 64 + mi * 16 + lg * 4 + r;   // feature j
        int h = gi >> 7, d = gi & 127;
        #pragma unroll
        for (int ni = 0; ni < 4; ni++){
          int gj = n0 + wn * 64 + ni * 16 + lr;         // token i
          int b = gj >> 11, s = gj & 2047;
          O0[((size_t)(b * H_ + h) * D_ + d) * S_ + s] = f2bf(acc[mi][ni][r]);
        }
      }
  } else {
    #pragma unroll
    for (int mi = 0; mi < 4; mi++)
      #pragma unroll
      for (int r = 0; r < 4; r++){
        int i = m0 + wm * 64 + mi * 16 + lg * 4 + r;
        #pragma unroll
        for (int ni = 0; ni < 4; ni++){
          int j = n0 + wn * 64 + ni * 16 + lr;
          Of[(size_t)i * HID + j] = acc[mi][ni][r];
        }
      }
  }
}

// ---------- in-place RoPE on Q and K ([B,H,S,D] bf16) ----------
__global__ void rope_k(unsigned short* __restrict__ Q, unsigned short* __restrict__ K,
                       const float* __restrict__ ctab, const float* __restrict__ stab){
  int idx = blockIdx.x * 256 + threadIdx.x;
  unsigned short* P = (idx >= (1 << 20)) ? K : Q;
  int e  = idx & ((1 << 20) - 1);
  int g  = e & 15;
  int s  = (e >> 4) & 2047;
  int bh = e >> 15;
  int d0 = g * 4;
  size_t base = ((size_t)bh * S_ + s) * D_;
  us4 qa = *(us4*)(P + base + d0);
  us4 qb = *(us4*)(P + base + d0 + 64);
  fl4 ca = *(const fl4*)(ctab + s * D_ + d0);
  fl4 sa = *(const fl4*)(stab + s * D_ + d0);
  fl4 cb = *(const fl4*)(ctab + s * D_ + d0 + 64);
  fl4 sb = *(const fl4*)(stab + s * D_ + d0 + 64);
  us4 oa, ob;
  #pragma unroll
  for (int t = 0; t < 4; t++){
    float xa = bf2f(qa[t]), xb = bf2f(qb[t]);
    oa[t] = f2bf(xa * ca[t] - xb * sa[t]);
    ob[t] = f2bf(xb * cb[t] + xa * sb[t]);
  }
  *(us4*)(P + base + d0)      = oa;
  *(us4*)(P + base + d0 + 64) = ob;
}

// ---------- flash attention: swapped QK^T + XOR-swizzled LDS K/V^T tiles ----------
// 4 waves x 16 q-rows, KVBLK=64. K tile [64][128], V^T tile [128][64], both
// swizzled: 16B-slot index ^= (row & 7)  ->  all b128 reads <=2-way (free).
__global__ __launch_bounds__(256) void attn_k(
    const unsigned short* __restrict__ Q,     // [B,H,S,D] (rope'd)
    const unsigned short* __restrict__ Kg,    // [B,H,S,D] (rope'd)
    const unsigned short* __restrict__ Vt,    // [B,H,D,S]
    const float* __restrict__ mask,           // [S,S]
    const float* __restrict__ alibi,          // [H,S]
    unsigned short* __restrict__ Ctx)         // [B,S,H,D]
{
  __shared__ __align__(16) unsigned short Kl[64 * 128];   // 16 KB
  __shared__ __align__(16) unsigned short Vl[128 * 64];   // 16 KB
  const int tid = threadIdx.x;
  const int l = tid & 63, lg = l >> 4, lr = l & 15;
  const int w = tid >> 6;
  const int bh = blockIdx.y, b = bh >> 4, h = bh & 15;
  const int q0 = blockIdx.x * 64 + w * 16;
  const size_t hb = (size_t)bh * S_ * D_;
  const float* mrow = mask + (size_t)(q0 + lr) * S_;
  const float* al = alibi + h * S_;
  const int sidx = (l & 48) + ((l & 48) >> 2);
  const float SCL2E = 0.08838834764831845f * 1.4426950408889634f;
  const float L2E = 1.4426950408889634f;

  // staging maps (coalesced 64B per thread from global)
  const int krow = tid >> 2;                  // 0..63
  const int vrow = tid >> 1;                  // 0..127 (d)
  const unsigned short* gK = Kg + hb + (size_t)krow * D_ + (tid & 3) * 32;
  const unsigned short* gV = Vt + hb + (size_t)vrow * S_ + (tid & 1) * 32;
  int kw[4], vw[4];
  #pragma unroll
  for (int i = 0; i < 4; i++){
    kw[i] = krow * 128 + ((((tid & 3) * 4 + i) ^ (krow & 7)) * 8);
    vw[i] = vrow * 64  + ((((tid & 1) * 4 + i) ^ (vrow & 7)) * 8);
  }

  short8 qf[4];
  #pragma unroll
  for (int c = 0; c < 4; c++)
    qf[c] = *(const short8*)(Q + hb + (size_t)(q0 + lr) * D_ + c * 32 + lg * 8);

  f32x4 acc[8];
  #pragma unroll
  for (int c = 0; c < 8; c++) acc[c] = f32x4{0.f, 0.f, 0.f, 0.f};
  float mr = -1e30f, lsum = 0.f;

  for (int t = 0; t < 32; t++){
    const int kv0 = t * 64;
    short8 ks[4], vs[4];
    #pragma unroll
    for (int i = 0; i < 4; i++) ks[i] = *(const short8*)(gK + (size_t)kv0 * D_ + i * 8);
    #pragma unroll
    for (int i = 0; i < 4; i++) vs[i] = *(const short8*)(gV + kv0 + i * 8);
    __syncthreads();                          // prev iter's LDS reads done
    #pragma unroll
    for (int i = 0; i < 4; i++) *(short8*)(Kl + kw[i]) = ks[i];
    #pragma unroll
    for (int i = 0; i < 4; i++) *(short8*)(Vl + vw[i]) = vs[i];
    __syncthreads();                          // tiles ready

    // S^T[k][q]: 4 k-groups of 16
    f32x4 sg[4];
    #pragma unroll
    for (int g = 0; g < 4; g++) sg[g] = f32x4{0.f, 0.f, 0.f, 0.f};
    #pragma unroll
    for (int g = 0; g < 4; g++){
      const int row = g * 16 + lr;
      #pragma unroll
      for (int c = 0; c < 4; c++){
        short8 kf = *(const short8*)(Kl + row * 128 + (((c * 4 + lg) ^ (row & 7)) * 8));
        sg[g] = __builtin_amdgcn_mfma_f32_16x16x32_bf16(kf, qf[c], sg[g], 0, 0, 0);
      }
    }

    // bias + softmax (lane holds k = kv0 + 16g + 4*lg + r, col q = q0+lr)
    float x[4][4];
    #pragma unroll
    for (int g = 0; g < 4; g++){
      fl4 mk = *(const fl4*)(mrow + kv0 + g * 16 + 4 * lg);
      fl4 aa = *(const fl4*)(al  + kv0 + g * 16 + 4 * lg);
      #pragma unroll
      for (int r = 0; r < 4; r++)
        x[g][r] = fmaf(sg[g][r], SCL2E, (mk[r] + aa[r]) * L2E);
    }
    float mx = -1e30f;
    #pragma unroll
    for (int g = 0; g < 4; g++)
      #pragma unroll
      for (int r = 0; r < 4; r++) mx = fmaxf(mx, x[g][r]);
    mx = fmaxf(mx, __shfl_xor(mx, 16));
    mx = fmaxf(mx, __shfl_xor(mx, 32));
    float mnew = fmaxf(mr, mx);
    float alpha = exp2f(mr - mnew);
    float p[4][4], ps = 0.f;
    #pragma unroll
    for (int g = 0; g < 4; g++)
      #pragma unroll
      for (int r = 0; r < 4; r++){
        p[g][r] = exp2f(x[g][r] - mnew);
        ps += p[g][r];
      }
    ps += __shfl_xor(ps, 16);
    ps += __shfl_xor(ps, 32);
    lsum = lsum * alpha + ps;
    mr = mnew;

    int pk0[4], pk1[4];
    #pragma unroll
    for (int r = 0; r < 4; r++){
      pk0[r] = ((int)(unsigned)f2bf(p[1][r]) << 16) | (int)(unsigned)f2bf(p[0][r]);
      pk1[r] = ((int)(unsigned)f2bf(p[3][r]) << 16) | (int)(unsigned)f2bf(p[2][r]);
    }

    float ar[4];
    #pragma unroll
    for (int r = 0; r < 4; r++) ar[r] = __shfl(alpha, sidx + r);
    #pragma unroll
    for (int c = 0; c < 8; c++)
      #pragma unroll
      for (int r = 0; r < 4; r++) acc[c][r] *= ar[r];

    // redistribute: lane needs P[q=lr][k = 8*lg + j] (af0: k<32, af1: k>=32)
    const int srcb = lr + ((lg & 1) << 5);
    short8 af0, af1;
    #pragma unroll
    for (int j = 0; j < 8; j++){
      int w0 = __shfl(pk0[j & 3], srcb + ((j >> 2) << 4));
      int w1 = __shfl(pk1[j & 3], srcb + ((j >> 2) << 4));
      af0[j] = (short)((l & 32) ? ((unsigned)w0 >> 16) : ((unsigned)w0 & 0xffffu));
      af1[j] = (short)((l & 32) ? ((unsigned)w1 >> 16) : ((unsigned)w1 & 0xffffu));
    }

    // PV: acc[c] += P(16x64) · V^T chunks (V^T tile rows d, swizzled)
    #pragma unroll
    for (int c = 0; c < 8; c++){
      const int d0 = c * 16 + lr;
      short8 vf0 = *(const short8*)(Vl + d0 * 64 + ((lg       ^ (d0 & 7)) * 8));
      short8 vf1 = *(const short8*)(Vl + d0 * 64 + (((4 + lg) ^ (d0 & 7)) * 8));
      acc[c] = __builtin_amdgcn_mfma_f32_16x16x32_bf16(af0, vf0, acc[c], 0, 0, 0);
      acc[c] = __builtin_amdgcn_mfma_f32_16x16x32_bf16(af1, vf1, acc[c], 0, 0, 0);
    }
  }

  float inv = 1.f / lsum;
  float ir[4];
  #pragma unroll
  for (int r = 0; r < 4; r++) ir[r] = __shfl(inv, sidx + r);
  #pragma unroll
  for (int r = 0; r < 4; r++){
    const int qg = q0 + 4 * lg + r;
    const size_t ob = ((size_t)(b * S_ + qg) * H_ + h) * D_;
    #pragma unroll
    for (int c = 0; c < 8; c++)
      Ctx[ob + c * 16 + lr] = f2bf(acc[c][r] * ir[r]);
  }
}

extern "C" void kernel_launch(void* const* d_in, const int* in_sizes, int n_in,
                              void* d_out, int out_size, void* d_ws, size_t ws_size,
                              hipStream_t stream){
  const float* x     = (const float*)d_in[0];
  const float* mask  = (const float*)d_in[1];
  const float* alibi = (const float*)d_in[2];
  const float* freqs = (const float*)d_in[3];
  const float* Wq    = (const float*)d_in[4];
  const float* Wk    = (const float*)d_in[5];
  const float* Wv    = (const float*)d_in[6];
  const float* Wo    = (const float*)d_in[7];
  float* out = (float*)d_out;

  unsigned short* ws  = (unsigned short*)d_ws;
  unsigned short* xb  = ws;
  unsigned short* wqb = ws + 8388608;
  unsigned short* wkb = ws + 12582912;
  unsigned short* wvb = ws + 16777216;
  unsigned short* wob = ws + 20971520;
  unsigned short* Qb  = ws + 25165824;
  unsigned short* Kb  = ws + 33554432;
  unsigned short* Vb  = ws + 41943040;         // V^T [B,H,D,S]
  unsigned short* ctx = xb;
  float* ctab = (float*)(ws + 50331648);
  float* stab = ctab + 262144;

  cvt_k<<<8192, 256, 0, stream>>>(x,  xb);
  cvt_k<<<4096, 256, 0, stream>>>(Wq, wqb);
  cvt_k<<<4096, 256, 0, stream>>>(Wk, wkb);
  cvt_k<<<4096, 256, 0, stream>>>(Wv, wvb);
  cvt_k<<<4096, 256, 0, stream>>>(Wo, wob);
  tab_k<<<1024, 256, 0, stream>>>(freqs, ctab, stab);

  gemm_k<1><<<dim3(32, 16, 2), 256, 0, stream>>>(xb, wqb, wkb, Qb, Kb, nullptr);
  gemm_k<2><<<dim3(16, 32, 1), 256, 0, stream>>>(wvb, xb, nullptr, Vb, nullptr, nullptr);
  rope_k<<<8192, 256, 0, stream>>>(Qb, Kb, ctab, stab);
  attn_k<<<dim3(32, 32), 256, 0, stream>>>(Qb, Kb, Vb, mask, alibi, ctx);
  gemm_k<0><<<dim3(32, 16, 1), 256, 0, stream>>>(ctx, wob, nullptr, nullptr, nullptr, out);
}

// Round 4
// 562.328 us; speedup vs baseline: 1.5556x; 1.0191x over previous
//
#include <hip/hip_runtime.h>
#include <math.h>

typedef __attribute__((ext_vector_type(8))) short short8;
typedef __attribute__((ext_vector_type(4))) float f32x4;
typedef __attribute__((ext_vector_type(4))) unsigned short us4;
typedef __attribute__((ext_vector_type(4))) float fl4;

#define B_ 2
#define S_ 2048
#define H_ 16
#define D_ 128
#define HID 2048

__device__ __forceinline__ unsigned short f2bf(float f){
  unsigned u = __builtin_bit_cast(unsigned, f);
  u += 0x7fffu + ((u >> 16) & 1u);
  return (unsigned short)(u >> 16);
}
__device__ __forceinline__ float bf2f(unsigned short u){
  unsigned x = ((unsigned)u) << 16;
  return __builtin_bit_cast(float, x);
}
// packed f32x2 -> bf16x2 (RNE), lo=first arg
__device__ __forceinline__ int cvtpk(float lo, float hi){
  int r; asm("v_cvt_pk_bf16_f32 %0, %1, %2" : "=v"(r) : "v"(lo), "v"(hi)); return r;
}

// async global -> LDS, 16 bytes per lane (dest must be linear: base + lane*16)
__device__ __forceinline__ void g2lds16(const unsigned short* g, unsigned short* l){
  __builtin_amdgcn_global_load_lds(
      (const __attribute__((address_space(1))) unsigned int*)g,
      (__attribute__((address_space(3))) unsigned int*)l, 16, 0, 0);
}

// ---------- f32 -> bf16 convert ----------
__global__ void cvt_k(const float* __restrict__ src, unsigned short* __restrict__ dst){
  int i = (blockIdx.x * 256 + threadIdx.x) * 4;
  fl4 v = *(const fl4*)(src + i);
  us4 o;
  #pragma unroll
  for (int t = 0; t < 4; t++) o[t] = f2bf(v[t]);
  *(us4*)(dst + i) = o;
}

// ---------- cos/sin tables ----------
__global__ void tab_k(const float* __restrict__ freqs, float* __restrict__ ctab,
                      float* __restrict__ stab){
  int i = blockIdx.x * 256 + threadIdx.x;
  float f = freqs[i];
  ctab[i] = cosf(f);
  stab[i] = sinf(f);
}

// ---------- GEMM: C[i][j] = sum_k A[i][k] * B[j][k]  (2-phase double-buffered) ----------
template<int EPI>
__global__ __launch_bounds__(256) void gemm_k(
    const unsigned short* __restrict__ A,
    const unsigned short* __restrict__ B0,
    const unsigned short* __restrict__ B1,
    unsigned short* __restrict__ O0,
    unsigned short* __restrict__ O1,
    float* __restrict__ Of)
{
  __shared__ __align__(16) unsigned short As[2][128 * 32];
  __shared__ __align__(16) unsigned short Bs[2][128 * 32];
  const int tid = threadIdx.x;
  const int l = tid & 63, lg = l >> 4, lr = l & 15;
  const int w = tid >> 6, wm = w & 1, wn = w >> 1;
  const int m0 = blockIdx.x * 128, n0 = blockIdx.y * 128;
  const unsigned short* Bm = (EPI == 1 && blockIdx.z == 1) ? B1 : B0;

  f32x4 acc[4][4];
  #pragma unroll
  for (int i = 0; i < 4; i++)
    #pragma unroll
    for (int j = 0; j < 4; j++)
      acc[i][j] = f32x4{0.f, 0.f, 0.f, 0.f};

  const unsigned short* gA = A  + (size_t)(m0 + (tid >> 2)) * HID + (tid & 3) * 8;
  const unsigned short* gB = Bm + (size_t)(n0 + (tid >> 2)) * HID + (tid & 3) * 8;

  #define GSTAGE(buf, kt) do {                                   \
    g2lds16(gA + (kt),            As[buf] + tid * 8);            \
    g2lds16(gA + 64 * HID + (kt), As[buf] + 2048 + tid * 8);     \
    g2lds16(gB + (kt),            Bs[buf] + tid * 8);            \
    g2lds16(gB + 64 * HID + (kt), Bs[buf] + 2048 + tid * 8);     \
  } while (0)

  GSTAGE(0, 0);
  __syncthreads();                         // drains vmcnt -> tile 0 ready
  int cur = 0;
  for (int t = 0; t < 64; t++){
    if (t < 63) GSTAGE(cur ^ 1, (t + 1) * 32);   // in flight during compute
    short8 aF[4], bF[4];
    #pragma unroll
    for (int mi = 0; mi < 4; mi++)
      aF[mi] = *(const short8*)(As[cur] + (wm * 64 + mi * 16 + lr) * 32 + lg * 8);
    #pragma unroll
    for (int ni = 0; ni < 4; ni++)
      bF[ni] = *(const short8*)(Bs[cur] + (wn * 64 + ni * 16 + lr) * 32 + lg * 8);
    #pragma unroll
    for (int mi = 0; mi < 4; mi++)
      #pragma unroll
      for (int ni = 0; ni < 4; ni++)
        acc[mi][ni] = __builtin_amdgcn_mfma_f32_16x16x32_bf16(aF[mi], bF[ni], acc[mi][ni], 0, 0, 0);
    __syncthreads();                       // reads done + next tile landed
    cur ^= 1;
  }
  #undef GSTAGE

  if (EPI == 1){
    unsigned short* O = blockIdx.z ? O1 : O0;
    #pragma unroll
    for (int mi = 0; mi < 4; mi++)
      #pragma unroll
      for (int r = 0; r < 4; r++){
        int i = m0 + wm * 64 + mi * 16 + lg * 4 + r;
        int b = i >> 11, s = i & 2047;
        #pragma unroll
        for (int ni = 0; ni < 4; ni++){
          int j = n0 + wn * 64 + ni * 16 + lr;
          int h = j >> 7, d = j & 127;
          O[((size_t)(b * H_ + h) * S_ + s) * D_ + d] = f2bf(acc[mi][ni][r]);
        }
      }
  } else if (EPI == 2){
    #pragma unroll
    for (int mi = 0; mi < 4; mi++)
      #pragma unroll
      for (int r = 0; r < 4; r++){
        int gi = m0 + wm * 64 + mi * 16 + lg * 4 + r;   // feature
        int h = gi >> 7, d = gi & 127;
        #pragma unroll
        for (int ni = 0; ni < 4; ni++){
          int gj = n0 + wn * 64 + ni * 16 + lr;         // token
          int b = gj >> 11, s = gj & 2047;
          O0[((size_t)(b * H_ + h) * D_ + d) * S_ + s] = f2bf(acc[mi][ni][r]);
        }
      }
  } else {
    #pragma unroll
    for (int mi = 0; mi < 4; mi++)
      #pragma unroll
      for (int r = 0; r < 4; r++){
        int i = m0 + wm * 64 + mi * 16 + lg * 4 + r;
        #pragma unroll
        for (int ni = 0; ni < 4; ni++){
          int j = n0 + wn * 64 + ni * 16 + lr;
          Of[(size_t)i * HID + j] = acc[mi][ni][r];
        }
      }
  }
}

// ---------- in-place RoPE on Q and K ----------
__global__ void rope_k(unsigned short* __restrict__ Q, unsigned short* __restrict__ K,
                       const float* __restrict__ ctab, const float* __restrict__ stab){
  int idx = blockIdx.x * 256 + threadIdx.x;
  unsigned short* P = (idx >= (1 << 20)) ? K : Q;
  int e  = idx & ((1 << 20) - 1);
  int g  = e & 15;
  int s  = (e >> 4) & 2047;
  int bh = e >> 15;
  int d0 = g * 4;
  size_t base = ((size_t)bh * S_ + s) * D_;
  us4 qa = *(us4*)(P + base + d0);
  us4 qb = *(us4*)(P + base + d0 + 64);
  fl4 ca = *(const fl4*)(ctab + s * D_ + d0);
  fl4 sa = *(const fl4*)(stab + s * D_ + d0);
  fl4 cb = *(const fl4*)(ctab + s * D_ + d0 + 64);
  fl4 sb = *(const fl4*)(stab + s * D_ + d0 + 64);
  us4 oa, ob;
  #pragma unroll
  for (int t = 0; t < 4; t++){
    float xa = bf2f(qa[t]), xb = bf2f(qb[t]);
    oa[t] = f2bf(xa * ca[t] - xb * sa[t]);
    ob[t] = f2bf(xb * cb[t] + xa * sb[t]);
  }
  *(us4*)(P + base + d0)      = oa;
  *(us4*)(P + base + d0 + 64) = ob;
}

// ---------- flash attention: dbuf g2lds (pre-swizzled src), defer-max, cvt_pk ----------
__global__ __launch_bounds__(256) void attn_k(
    const unsigned short* __restrict__ Q,     // [B,H,S,D] (rope'd)
    const unsigned short* __restrict__ Kg,    // [B,H,S,D] (rope'd)
    const unsigned short* __restrict__ Vt,    // [B,H,D,S]
    const float* __restrict__ mask,           // [S,S]
    const float* __restrict__ alibi,          // [H,S]
    unsigned short* __restrict__ Ctx)         // [B,S,H,D]
{
  __shared__ __align__(16) unsigned short Kl[2][64 * 128];  // 32 KB
  __shared__ __align__(16) unsigned short Vl[2][128 * 64];  // 32 KB
  const int tid = threadIdx.x;
  const int l = tid & 63, lg = l >> 4, lr = l & 15;
  const int w = tid >> 6;
  const int bh = blockIdx.y, b = bh >> 4, h = bh & 15;
  const int q0 = blockIdx.x * 64 + w * 16;
  const size_t hb = (size_t)bh * S_ * D_;
  const float* mrow = mask + (size_t)(q0 + lr) * S_;
  const float* al = alibi + h * S_;
  const int sidx = (l & 48) + ((l & 48) >> 2);
  const float SCL2E = 0.08838834764831845f * 1.4426950408889634f;
  const float L2E = 1.4426950408889634f;

  // staging: pre-swizzled GLOBAL source, LINEAR LDS dest (rule #21 combo).
  // K tile [64][128]: granule (16B) slot 0..15 per row; row&7 lane-const.
  const int kswz = (((tid & 15) ^ ((tid >> 4) & 7)) * 8);
  const unsigned short* gK = Kg + hb + (size_t)(tid >> 4) * D_ + kswz;
  // V^T tile [128][64]: slot 0..7 per row.
  const int vswz = (((tid & 7) ^ ((tid >> 3) & 7)) * 8);
  const unsigned short* gV = Vt + hb + (size_t)(tid >> 3) * S_ + vswz;

  #define ASTAGE(buf, kv)  do {                                            \
    g2lds16(gK + (size_t)((kv))      * D_, Kl[buf] + tid * 8);             \
    g2lds16(gK + (size_t)((kv) + 16) * D_, Kl[buf] + 2048 + tid * 8);      \
    g2lds16(gK + (size_t)((kv) + 32) * D_, Kl[buf] + 4096 + tid * 8);      \
    g2lds16(gK + (size_t)((kv) + 48) * D_, Kl[buf] + 6144 + tid * 8);      \
    g2lds16(gV + (kv),                     Vl[buf] + tid * 8);             \
    g2lds16(gV + 32 * S_ + (kv),           Vl[buf] + 2048 + tid * 8);      \
    g2lds16(gV + 64 * S_ + (kv),           Vl[buf] + 4096 + tid * 8);      \
    g2lds16(gV + 96 * S_ + (kv),           Vl[buf] + 6144 + tid * 8);      \
  } while (0)

  // loop-invariant swizzled read offsets (row&7 == lr&7 for all our rows)
  int koff[4];
  #pragma unroll
  for (int c = 0; c < 4; c++) koff[c] = ((c * 4 + lg) ^ (lr & 7)) * 8;
  const int vo0 = (lg ^ (lr & 7)) * 8, vo1 = ((4 + lg) ^ (lr & 7)) * 8;

  short8 qf[4];
  #pragma unroll
  for (int c = 0; c < 4; c++)
    qf[c] = *(const short8*)(Q + hb + (size_t)(q0 + lr) * D_ + c * 32 + lg * 8);

  f32x4 acc[8];
  #pragma unroll
  for (int c = 0; c < 8; c++) acc[c] = f32x4{0.f, 0.f, 0.f, 0.f};
  float mr = -1e30f, lsum = 0.f;

  ASTAGE(0, 0);
  __syncthreads();
  int cur = 0;

  for (int t = 0; t < 32; t++){
    const int kv0 = t * 64;
    if (t < 31) ASTAGE(cur ^ 1, kv0 + 64);   // in flight during compute

    // hoist mask/alibi loads ahead of QK^T MFMAs
    fl4 mk[4], aa[4];
    #pragma unroll
    for (int g = 0; g < 4; g++){
      mk[g] = *(const fl4*)(mrow + kv0 + g * 16 + 4 * lg);
      aa[g] = *(const fl4*)(al  + kv0 + g * 16 + 4 * lg);
    }

    // S^T[k][q] = K · Q^T
    f32x4 sg[4];
    #pragma unroll
    for (int g = 0; g < 4; g++) sg[g] = f32x4{0.f, 0.f, 0.f, 0.f};
    #pragma unroll
    for (int g = 0; g < 4; g++){
      const int row = g * 16 + lr;
      #pragma unroll
      for (int c = 0; c < 4; c++){
        short8 kf = *(const short8*)(Kl[cur] + row * 128 + koff[c]);
        sg[g] = __builtin_amdgcn_mfma_f32_16x16x32_bf16(kf, qf[c], sg[g], 0, 0, 0);
      }
    }

    float x[4][4];
    #pragma unroll
    for (int g = 0; g < 4; g++)
      #pragma unroll
      for (int r = 0; r < 4; r++)
        x[g][r] = fmaf(sg[g][r], SCL2E, (mk[g][r] + aa[g][r]) * L2E);

    float mx = -1e30f;
    #pragma unroll
    for (int g = 0; g < 4; g++)
      #pragma unroll
      for (int r = 0; r < 4; r++) mx = fmaxf(mx, x[g][r]);

    float p[4][4], ps = 0.f;
    if (__all(mx <= mr + 8.f)){
      // defer-max: no rescale, no cross-lane max (P bounded by 2^8)
      #pragma unroll
      for (int g = 0; g < 4; g++)
        #pragma unroll
        for (int r = 0; r < 4; r++){
          p[g][r] = exp2f(x[g][r] - mr);
          ps += p[g][r];
        }
      ps += __shfl_xor(ps, 16);
      ps += __shfl_xor(ps, 32);
      lsum += ps;
    } else {
      mx = fmaxf(mx, __shfl_xor(mx, 16));
      mx = fmaxf(mx, __shfl_xor(mx, 32));
      float mnew = fmaxf(mr, mx);
      float alpha = exp2f(mr - mnew);
      #pragma unroll
      for (int g = 0; g < 4; g++)
        #pragma unroll
        for (int r = 0; r < 4; r++){
          p[g][r] = exp2f(x[g][r] - mnew);
          ps += p[g][r];
        }
      ps += __shfl_xor(ps, 16);
      ps += __shfl_xor(ps, 32);
      lsum = lsum * alpha + ps;
      mr = mnew;
      float ar[4];
      #pragma unroll
      for (int r = 0; r < 4; r++) ar[r] = __shfl(alpha, sidx + r);
      #pragma unroll
      for (int c = 0; c < 8; c++)
        #pragma unroll
        for (int r = 0; r < 4; r++) acc[c][r] *= ar[r];
    }

    int pk0[4], pk1[4];
    #pragma unroll
    for (int r = 0; r < 4; r++){
      pk0[r] = cvtpk(p[0][r], p[1][r]);
      pk1[r] = cvtpk(p[2][r], p[3][r]);
    }

    // redistribute: lane needs P[q=lr][k = 8*lg + j]
    const int srcb = lr + ((lg & 1) << 5);
    short8 af0, af1;
    #pragma unroll
    for (int j = 0; j < 8; j++){
      int w0 = __shfl(pk0[j & 3], srcb + ((j >> 2) << 4));
      int w1 = __shfl(pk1[j & 3], srcb + ((j >> 2) << 4));
      af0[j] = (short)((l & 32) ? ((unsigned)w0 >> 16) : ((unsigned)w0 & 0xffffu));
      af1[j] = (short)((l & 32) ? ((unsigned)w1 >> 16) : ((unsigned)w1 & 0xffffu));
    }

    // PV
    #pragma unroll
    for (int c = 0; c < 8; c++){
      const int d0 = c * 16 + lr;
      short8 vf0 = *(const short8*)(Vl[cur] + d0 * 64 + vo0);
      short8 vf1 = *(const short8*)(Vl[cur] + d0 * 64 + vo1);
      acc[c] = __builtin_amdgcn_mfma_f32_16x16x32_bf16(af0, vf0, acc[c], 0, 0, 0);
      acc[c] = __builtin_amdgcn_mfma_f32_16x16x32_bf16(af1, vf1, acc[c], 0, 0, 0);
    }

    __syncthreads();                       // reads done + next tile landed
    cur ^= 1;
  }
  #undef ASTAGE

  float inv = 1.f / lsum;
  float ir[4];
  #pragma unroll
  for (int r = 0; r < 4; r++) ir[r] = __shfl(inv, sidx + r);
  #pragma unroll
  for (int r = 0; r < 4; r++){
    const int qg = q0 + 4 * lg + r;
    const size_t ob = ((size_t)(b * S_ + qg) * H_ + h) * D_;
    #pragma unroll
    for (int c = 0; c < 8; c++)
      Ctx[ob + c * 16 + lr] = f2bf(acc[c][r] * ir[r]);
  }
}

extern "C" void kernel_launch(void* const* d_in, const int* in_sizes, int n_in,
                              void* d_out, int out_size, void* d_ws, size_t ws_size,
                              hipStream_t stream){
  const float* x     = (const float*)d_in[0];
  const float* mask  = (const float*)d_in[1];
  const float* alibi = (const float*)d_in[2];
  const float* freqs = (const float*)d_in[3];
  const float* Wq    = (const float*)d_in[4];
  const float* Wk    = (const float*)d_in[5];
  const float* Wv    = (const float*)d_in[6];
  const float* Wo    = (const float*)d_in[7];
  float* out = (float*)d_out;

  unsigned short* ws  = (unsigned short*)d_ws;
  unsigned short* xb  = ws;
  unsigned short* wqb = ws + 8388608;
  unsigned short* wkb = ws + 12582912;
  unsigned short* wvb = ws + 16777216;
  unsigned short* wob = ws + 20971520;
  unsigned short* Qb  = ws + 25165824;
  unsigned short* Kb  = ws + 33554432;
  unsigned short* Vb  = ws + 41943040;         // V^T [B,H,D,S]
  unsigned short* ctx = xb;
  float* ctab = (float*)(ws + 50331648);
  float* stab = ctab + 262144;

  cvt_k<<<8192, 256, 0, stream>>>(x,  xb);
  cvt_k<<<4096, 256, 0, stream>>>(Wq, wqb);
  cvt_k<<<4096, 256, 0, stream>>>(Wk, wkb);
  cvt_k<<<4096, 256, 0, stream>>>(Wv, wvb);
  cvt_k<<<4096, 256, 0, stream>>>(Wo, wob);
  tab_k<<<1024, 256, 0, stream>>>(freqs, ctab, stab);

  gemm_k<1><<<dim3(32, 16, 2), 256, 0, stream>>>(xb, wqb, wkb, Qb, Kb, nullptr);
  gemm_k<2><<<dim3(16, 32, 1), 256, 0, stream>>>(wvb, xb, nullptr, Vb, nullptr, nullptr);
  rope_k<<<8192, 256, 0, stream>>>(Qb, Kb, ctab, stab);
  attn_k<<<dim3(32, 32), 256, 0, stream>>>(Qb, Kb, Vb, mask, alibi, ctx);
  gemm_k<0><<<dim3(32, 16, 1), 256, 0, stream>>>(ctx, wob, nullptr, nullptr, nullptr, out);
}